// Round 6
// baseline (215.262 us; speedup 1.0000x reference)
//
#include <hip/hip_runtime.h>
#include <hip/hip_bf16.h>
#include <stdint.h>

#define S_LEN 2048
#define D_DIM 64
#define HEADS 12
#define KVB   64
#define QBLK  64
#define NTILES (S_LEN / KVB)

typedef __attribute__((ext_vector_type(8))) short bf16x8;
typedef __attribute__((ext_vector_type(4))) float f32x4;

__device__ __forceinline__ unsigned short f2bf(float x) {
    union { float f; uint32_t u; } v; v.f = x;
    uint32_t r = v.u + 0x7FFFu + ((v.u >> 16) & 1u);   // RNE
    return (unsigned short)(r >> 16);
}
__device__ __forceinline__ float bf2f(unsigned short h) {
    union { uint32_t u; float f; } t; t.u = ((uint32_t)h) << 16; return t.f;
}
// split x into hi+lo bf16 (x ~ hi + lo, error ~2^-18 rel)
__device__ __forceinline__ void split2(float x, unsigned short& h, unsigned short& l) {
    h = f2bf(x);
    l = f2bf(x - bf2f(h));
}

__global__ __launch_bounds__(256, 3)
void attn_fwd(const float* __restrict__ Q, const float* __restrict__ K,
              const float* __restrict__ V, const float* __restrict__ M,
              float* __restrict__ O)
{
    // K tile hi/lo: [64 keys][64 d] bf16, XOR-swizzled rows (row stride 128B)
    __shared__ unsigned char klds_h[64 * 128];
    __shared__ unsigned char klds_l[64 * 128];
    // V^T tile [64 d][64 kk] bf16, XOR-swizzled rows
    __shared__ unsigned char vlds[64 * 128];

    const int bid  = blockIdx.x;
    const int bh   = bid >> 5;          // 0..23  (b*H + h)
    const int qb   = bid & 31;          // q-block
    const int b    = bh / HEADS;
    const long qkv_base  = (long)bh * S_LEN * D_DIM;
    const long mask_base = (long)b * S_LEN * S_LEN;

    const int tid  = threadIdx.x;
    const int wave = tid >> 6;
    const int lane = tid & 63;
    const int c    = lane & 15;         // MFMA "col" lane index
    const int g    = lane >> 4;         // lane group 0..3
    const int sw   = (c & 7) << 4;      // read-side XOR swizzle

    const int qrow = qb * QBLK + wave * 16 + c;   // this lane's query

    // ---- Q fragments hi/lo (B-operand of S^T = K * Q^T): lane holds Q[qrow][d] ----
    bf16x8 qfh[2], qfl[2];
    {
        const float* qp = Q + qkv_base + (long)qrow * D_DIM;
        #pragma unroll
        for (int f = 0; f < 2; ++f) {
            float4 x0 = *(const float4*)(qp + f * 32 + 8 * g);
            float4 x1 = *(const float4*)(qp + f * 32 + 8 * g + 4);
            float e[8] = { x0.x, x0.y, x0.z, x0.w, x1.x, x1.y, x1.z, x1.w };
            bf16x8 th, tl;
            #pragma unroll
            for (int j = 0; j < 8; ++j) {
                unsigned short h, l;
                split2(e[j], h, l);
                th[j] = (short)h; tl[j] = (short)l;
            }
            qfh[f] = th; qfl[f] = tl;
        }
    }

    f32x4 o[4] = {};                    // O^T accum: o[mt][r] -> d = 16*mt+4*g+r, q = qrow
    float m_run = -INFINITY, l_run = 0.f;
    const float* mrow = M + mask_base + (long)qrow * S_LEN;

    for (int t0 = 0; t0 < NTILES; ++t0) {
        const int k0 = t0 * KVB;

        // ---------- stage K tile hi+lo: [key][d] fp32 -> bf16 LDS, swizzled ----------
        {
            const float* kp = K + qkv_base + (long)k0 * D_DIM;
            #pragma unroll
            for (int it = 0; it < 4; ++it) {
                int i   = tid + 256 * it;       // 1024 float4 total
                int row = i >> 4;
                int c4  = i & 15;
                float4 x = *(const float4*)(kp + row * 64 + c4 * 4);
                unsigned short h0, l0, h1, l1, h2, l2, h3, l3;
                split2(x.x, h0, l0); split2(x.y, h1, l1);
                split2(x.z, h2, l2); split2(x.w, h3, l3);
                int off = row * 128 + ((c4 * 8) ^ ((row & 7) << 4));
                *(uint2*)(klds_h + off) =
                    make_uint2(((uint32_t)h1 << 16) | h0, ((uint32_t)h3 << 16) | h2);
                *(uint2*)(klds_l + off) =
                    make_uint2(((uint32_t)l1 << 16) | l0, ((uint32_t)l3 << 16) | l2);
            }
        }
        // ---------- stage V^T tile: vt[d][kk], transpose in flight ----------
        {
            const float* vp = V + qkv_base + (long)k0 * D_DIM;
            int d = tid & 63, a = tid >> 6;
            #pragma unroll
            for (int h = 0; h < 2; ++h) {
                int kk0 = 32 * h + 8 * a;
                uint32_t w0, w1, w2, w3;
                {   // 8 coalesced scalar loads (lane-fast index is d)
                    float e0 = vp[(kk0 + 0) * 64 + d], e1 = vp[(kk0 + 1) * 64 + d];
                    float e2 = vp[(kk0 + 2) * 64 + d], e3 = vp[(kk0 + 3) * 64 + d];
                    float e4 = vp[(kk0 + 4) * 64 + d], e5 = vp[(kk0 + 5) * 64 + d];
                    float e6 = vp[(kk0 + 6) * 64 + d], e7 = vp[(kk0 + 7) * 64 + d];
                    w0 = ((uint32_t)f2bf(e1) << 16) | f2bf(e0);
                    w1 = ((uint32_t)f2bf(e3) << 16) | f2bf(e2);
                    w2 = ((uint32_t)f2bf(e5) << 16) | f2bf(e4);
                    w3 = ((uint32_t)f2bf(e7) << 16) | f2bf(e6);
                }
                int off = d * 128 + ((kk0 * 2) ^ ((d & 7) << 4));
                *(uint4*)(vlds + off) = make_uint4(w0, w1, w2, w3);
            }
        }
        __syncthreads();

        // ---------- QK^T: S^T tiles, hi/lo compensated ----------
        f32x4 st[4];
        #pragma unroll
        for (int kt = 0; kt < 4; ++kt) {
            const unsigned char* bh_ = klds_h + (16 * kt + c) * 128;
            const unsigned char* bl_ = klds_l + (16 * kt + c) * 128;
            bf16x8 kh0 = *(const bf16x8*)(bh_ + ((16 * g) ^ sw));
            bf16x8 kh1 = *(const bf16x8*)(bh_ + ((64 + 16 * g) ^ sw));
            bf16x8 kl0 = *(const bf16x8*)(bl_ + ((16 * g) ^ sw));
            bf16x8 kl1 = *(const bf16x8*)(bl_ + ((64 + 16 * g) ^ sw));
            f32x4 acc = {};
            // small terms first: K_hi*Q_lo + K_lo*Q_hi + K_hi*Q_hi
            acc = __builtin_amdgcn_mfma_f32_16x16x32_bf16(kh0, qfl[0], acc, 0, 0, 0);
            acc = __builtin_amdgcn_mfma_f32_16x16x32_bf16(kh1, qfl[1], acc, 0, 0, 0);
            acc = __builtin_amdgcn_mfma_f32_16x16x32_bf16(kl0, qfh[0], acc, 0, 0, 0);
            acc = __builtin_amdgcn_mfma_f32_16x16x32_bf16(kl1, qfh[1], acc, 0, 0, 0);
            acc = __builtin_amdgcn_mfma_f32_16x16x32_bf16(kh0, qfh[0], acc, 0, 0, 0);
            acc = __builtin_amdgcn_mfma_f32_16x16x32_bf16(kh1, qfh[1], acc, 0, 0, 0);
            st[kt] = acc;   // S^T: row = key = 16*kt+4*g+r, col = q = c (our qrow)
        }

        // ---------- mask add + online softmax (per q = lane-local) ----------
        float p[4][4];
        float tmax = -INFINITY;
        #pragma unroll
        for (int kt = 0; kt < 4; ++kt)
            #pragma unroll
            for (int r = 0; r < 4; ++r) {
                float sc = st[kt][r] + mrow[k0 + 16 * kt + 4 * g + r];
                p[kt][r] = sc;
                tmax = fmaxf(tmax, sc);
            }
        tmax = fmaxf(tmax, __shfl_xor(tmax, 16, 64));
        tmax = fmaxf(tmax, __shfl_xor(tmax, 32, 64));
        float m_new = fmaxf(m_run, tmax);
        float scale = __expf(m_run - m_new);    // first tile: exp(-inf)=0
        float tsum = 0.f;
        #pragma unroll
        for (int kt = 0; kt < 4; ++kt)
            #pragma unroll
            for (int r = 0; r < 4; ++r) {
                float e = __expf(p[kt][r] - m_new);
                p[kt][r] = e;
                tsum += e;
            }
        tsum += __shfl_xor(tsum, 16, 64);
        tsum += __shfl_xor(tsum, 32, 64);
        l_run = l_run * scale + tsum;
        m_run = m_new;
        #pragma unroll
        for (int mt = 0; mt < 4; ++mt) o[mt] *= scale;

        // ---------- P -> bf16, redistribute S^T-layout -> B-fragment layout ----------
        // source: lane(gs,c) reg r holds P[q=c][key = 16*kt + 4*gs + r]
        // target: lane(g,c) word pp holds P[q=c][kk = 32*f + 8*g + {2pp,2pp+1}]
        uint32_t w[4][2];
        #pragma unroll
        for (int kt = 0; kt < 4; ++kt) {
            w[kt][0] = ((uint32_t)f2bf(p[kt][1]) << 16) | f2bf(p[kt][0]);
            w[kt][1] = ((uint32_t)f2bf(p[kt][3]) << 16) | f2bf(p[kt][2]);
        }
        bf16x8 pf[2];
        const bool hi_half = (lane & 32) != 0;  // g>>1 selects source kt parity
        #pragma unroll
        for (int f = 0; f < 2; ++f) {
            uint32_t words[4];
            #pragma unroll
            for (int pp = 0; pp < 4; ++pp) {
                int srcl = 16 * (2 * (g & 1) + (pp >> 1)) + c;
                int addr = srcl << 2;
                int lo = __builtin_amdgcn_ds_bpermute(addr, (int)w[2 * f][pp & 1]);
                int hi = __builtin_amdgcn_ds_bpermute(addr, (int)w[2 * f + 1][pp & 1]);
                words[pp] = hi_half ? (uint32_t)hi : (uint32_t)lo;
            }
            union { uint32_t u[4]; bf16x8 v; } cv;
            cv.u[0] = words[0]; cv.u[1] = words[1];
            cv.u[2] = words[2]; cv.u[3] = words[3];
            pf[f] = cv.v;
        }

        // ---------- PV: O^T += V^T * P^T ----------
        #pragma unroll
        for (int f = 0; f < 2; ++f) {
            #pragma unroll
            for (int mt = 0; mt < 4; ++mt) {
                const unsigned char* base = vlds + (16 * mt + c) * 128;
                bf16x8 vf = *(const bf16x8*)(base + ((64 * f + 16 * g) ^ sw));
                o[mt] = __builtin_amdgcn_mfma_f32_16x16x32_bf16(vf, pf[f], o[mt], 0, 0, 0);
            }
        }
        __syncthreads();
    }

    // ---------- epilogue: O[q][d] = O^T accum / l ----------
    float inv = 1.0f / l_run;
    float* op = O + qkv_base + (long)qrow * D_DIM;
    #pragma unroll
    for (int mt = 0; mt < 4; ++mt) {
        float4 x = make_float4(o[mt][0] * inv, o[mt][1] * inv,
                               o[mt][2] * inv, o[mt][3] * inv);
        *(float4*)(op + 16 * mt + 4 * g) = x;
    }
}

extern "C" void kernel_launch(void* const* d_in, const int* in_sizes, int n_in,
                              void* d_out, int out_size, void* d_ws, size_t ws_size,
                              hipStream_t stream) {
    const float* q = (const float*)d_in[0];
    const float* k = (const float*)d_in[1];
    const float* v = (const float*)d_in[2];
    const float* m = (const float*)d_in[3];
    float* o = (float*)d_out;
    dim3 grid(2 * HEADS * (S_LEN / QBLK));   // 768
    dim3 block(256);
    attn_fwd<<<grid, block, 0, stream>>>(q, k, v, m, o);
}

// Round 7
// 195.232 us; speedup vs baseline: 1.1026x; 1.1026x over previous
//
#include <hip/hip_runtime.h>
#include <hip/hip_bf16.h>
#include <stdint.h>

#define S_LEN 2048
#define D_DIM 64
#define HEADS 12
#define KVB   64
#define QBLK  64
#define NTILES (S_LEN / KVB)
#define BH    (2 * HEADS)                      // 24 (b*H)
#define TILE_BYTES 8192                        // one 64x64 bf16 tile image
#define KH_OFF ((size_t)0)
#define KL_OFF ((size_t)BH * NTILES * TILE_BYTES)          // 6291456
#define VT_OFF ((size_t)2 * BH * NTILES * TILE_BYTES)      // 12582912
#define WS_NEED ((size_t)3 * BH * NTILES * TILE_BYTES)     // 18874368

typedef __attribute__((ext_vector_type(8))) short bf16x8;
typedef __attribute__((ext_vector_type(4))) float f32x4;

__device__ __forceinline__ unsigned short f2bf(float x) {
    union { float f; uint32_t u; } v; v.f = x;
    uint32_t r = v.u + 0x7FFFu + ((v.u >> 16) & 1u);   // RNE
    return (unsigned short)(r >> 16);
}
__device__ __forceinline__ float bf2f(unsigned short h) {
    union { uint32_t u; float f; } t; t.u = ((uint32_t)h) << 16; return t.f;
}
__device__ __forceinline__ void split2(float x, unsigned short& h, unsigned short& l) {
    h = f2bf(x);
    l = f2bf(x - bf2f(h));
}
__device__ __forceinline__ void gload16(const void* g, void* l) {
    __builtin_amdgcn_global_load_lds(
        (const __attribute__((address_space(1))) void*)g,
        (__attribute__((address_space(3))) void*)l, 16, 0, 0);
}

// ---------- pre-pass: K -> (hi,lo) bf16 tile images, V -> V^T bf16 tile images.
// Byte-for-byte identical to what the old in-kernel staging wrote to LDS.
__global__ __launch_bounds__(256, 4)
void convert_kv(const float* __restrict__ K, const float* __restrict__ V,
                unsigned char* __restrict__ ws)
{
    const int blk = blockIdx.x;          // bh*NTILES + t
    const int bh  = blk >> 5;
    const int t   = blk & 31;
    const long qkv_base = (long)bh * S_LEN * D_DIM;
    const int tid = threadIdx.x;
    unsigned char* kh = ws + KH_OFF + (size_t)blk * TILE_BYTES;
    unsigned char* kl = ws + KL_OFF + (size_t)blk * TILE_BYTES;
    unsigned char* vt = ws + VT_OFF + (size_t)blk * TILE_BYTES;
    const int k0 = t * KVB;

    const float* kp = K + qkv_base + (long)k0 * D_DIM;
    #pragma unroll
    for (int it = 0; it < 4; ++it) {
        int i   = tid + 256 * it;
        int row = i >> 4;
        int c4  = i & 15;
        float4 x = *(const float4*)(kp + row * 64 + c4 * 4);
        unsigned short h0, l0, h1, l1, h2, l2, h3, l3;
        split2(x.x, h0, l0); split2(x.y, h1, l1);
        split2(x.z, h2, l2); split2(x.w, h3, l3);
        int off = row * 128 + ((c4 * 8) ^ ((row & 7) << 4));
        *(uint2*)(kh + off) = make_uint2(((uint32_t)h1 << 16) | h0, ((uint32_t)h3 << 16) | h2);
        *(uint2*)(kl + off) = make_uint2(((uint32_t)l1 << 16) | l0, ((uint32_t)l3 << 16) | l2);
    }

    const float* vp = V + qkv_base + (long)k0 * D_DIM;
    int d = tid & 63, a = tid >> 6;
    #pragma unroll
    for (int h = 0; h < 2; ++h) {
        int kk0 = 32 * h + 8 * a;
        float e0 = vp[(kk0 + 0) * 64 + d], e1 = vp[(kk0 + 1) * 64 + d];
        float e2 = vp[(kk0 + 2) * 64 + d], e3 = vp[(kk0 + 3) * 64 + d];
        float e4 = vp[(kk0 + 4) * 64 + d], e5 = vp[(kk0 + 5) * 64 + d];
        float e6 = vp[(kk0 + 6) * 64 + d], e7 = vp[(kk0 + 7) * 64 + d];
        uint32_t w0 = ((uint32_t)f2bf(e1) << 16) | f2bf(e0);
        uint32_t w1 = ((uint32_t)f2bf(e3) << 16) | f2bf(e2);
        uint32_t w2 = ((uint32_t)f2bf(e5) << 16) | f2bf(e4);
        uint32_t w3 = ((uint32_t)f2bf(e7) << 16) | f2bf(e6);
        int off = d * 128 + ((kk0 * 2) ^ ((d & 7) << 4));
        *(uint4*)(vt + off) = make_uint4(w0, w1, w2, w3);
    }
}

// ---------- fast attention: DMA-staged K/V tiles from ws, LDS-staged mask tile
__global__ __launch_bounds__(256, 3)
void attn_fwd_ws(const float* __restrict__ Q, const float* __restrict__ M,
                 const unsigned char* __restrict__ ws, float* __restrict__ O)
{
    __shared__ unsigned char klds_h[8192];
    __shared__ unsigned char klds_l[8192];
    __shared__ unsigned char vlds[8192];
    __shared__ unsigned char mlds[16384];   // mask tile [64 q][64 k] fp32, row-XOR-swizzled

    const int bid  = blockIdx.x;
    const int bh   = bid >> 5;
    const int qb   = bid & 31;
    const int b    = bh / HEADS;
    const long qkv_base  = (long)bh * S_LEN * D_DIM;
    const long mask_base = (long)b * S_LEN * S_LEN;

    const int tid  = threadIdx.x;
    const int wave = tid >> 6;
    const int lane = tid & 63;
    const int c    = lane & 15;
    const int g    = lane >> 4;
    const int sw   = (c & 7) << 4;

    const int qrow = qb * QBLK + wave * 16 + c;

    // ---- Q fragments hi/lo ----
    bf16x8 qfh[2], qfl[2];
    {
        const float* qp = Q + qkv_base + (long)qrow * D_DIM;
        #pragma unroll
        for (int f = 0; f < 2; ++f) {
            float4 x0 = *(const float4*)(qp + f * 32 + 8 * g);
            float4 x1 = *(const float4*)(qp + f * 32 + 8 * g + 4);
            float e[8] = { x0.x, x0.y, x0.z, x0.w, x1.x, x1.y, x1.z, x1.w };
            bf16x8 th, tl;
            #pragma unroll
            for (int j = 0; j < 8; ++j) {
                unsigned short h, l;
                split2(e[j], h, l);
                th[j] = (short)h; tl[j] = (short)l;
            }
            qfh[f] = th; qfl[f] = tl;
        }
    }

    const unsigned char* khB = ws + KH_OFF + (size_t)bh * NTILES * TILE_BYTES;
    const unsigned char* klB = ws + KL_OFF + (size_t)bh * NTILES * TILE_BYTES;
    const unsigned char* vtB = ws + VT_OFF + (size_t)bh * NTILES * TILE_BYTES;
    const float* mrow0 = M + mask_base + (long)(qb * QBLK) * S_LEN;  // mask row block base

    f32x4 o[4] = {};
    float m_run = -INFINITY, l_run = 0.f;

    for (int t0 = 0; t0 < NTILES; ++t0) {
        const unsigned char* khT = khB + (size_t)t0 * TILE_BYTES;
        const unsigned char* klT = klB + (size_t)t0 * TILE_BYTES;
        const unsigned char* vtT = vtB + (size_t)t0 * TILE_BYTES;

        // ---------- stage K(hi,lo) + V^T via direct-to-LDS DMA (linear copy) ----------
        #pragma unroll
        for (int j = 0; j < 2; ++j) {
            int o2 = wave * 2048 + j * 1024;
            gload16(khT + o2 + lane * 16, klds_h + o2);
            gload16(klT + o2 + lane * 16, klds_l + o2);
            gload16(vtT + o2 + lane * 16, vlds + o2);
        }
        // ---------- stage mask tile: per-lane global gather -> linear LDS ----------
        #pragma unroll
        for (int j = 0; j < 4; ++j) {
            int o2 = wave * 4096 + j * 1024;          // wave-uniform LDS dest base
            int X  = o2 + lane * 16;                  // this lane's dest byte
            int q  = X >> 8;                          // tile q-row 0..63
            int ib = X & 255;                         // byte within row
            const unsigned char* gm =
                (const unsigned char*)(mrow0 + (long)q * S_LEN) + t0 * 256;
            gload16(gm + (ib ^ ((q & 7) << 4)), mlds + o2);
        }
        __syncthreads();

        // ---------- QK^T: S^T tiles, hi/lo compensated ----------
        f32x4 st[4];
        #pragma unroll
        for (int kt = 0; kt < 4; ++kt) {
            const unsigned char* bh_ = klds_h + (16 * kt + c) * 128;
            const unsigned char* bl_ = klds_l + (16 * kt + c) * 128;
            bf16x8 kh0 = *(const bf16x8*)(bh_ + ((16 * g) ^ sw));
            bf16x8 kh1 = *(const bf16x8*)(bh_ + ((64 + 16 * g) ^ sw));
            bf16x8 kl0 = *(const bf16x8*)(bl_ + ((16 * g) ^ sw));
            bf16x8 kl1 = *(const bf16x8*)(bl_ + ((64 + 16 * g) ^ sw));
            f32x4 acc = {};
            acc = __builtin_amdgcn_mfma_f32_16x16x32_bf16(kh0, qfl[0], acc, 0, 0, 0);
            acc = __builtin_amdgcn_mfma_f32_16x16x32_bf16(kh1, qfl[1], acc, 0, 0, 0);
            acc = __builtin_amdgcn_mfma_f32_16x16x32_bf16(kl0, qfh[0], acc, 0, 0, 0);
            acc = __builtin_amdgcn_mfma_f32_16x16x32_bf16(kl1, qfh[1], acc, 0, 0, 0);
            acc = __builtin_amdgcn_mfma_f32_16x16x32_bf16(kh0, qfh[0], acc, 0, 0, 0);
            acc = __builtin_amdgcn_mfma_f32_16x16x32_bf16(kh1, qfh[1], acc, 0, 0, 0);
            st[kt] = acc;
        }

        // ---------- mask add (from LDS tile) + online softmax ----------
        const int mq = wave * 16 + c;                 // this lane's tile q-row
        const unsigned char* mrl = mlds + mq * 256;   // (mq&7)==(c&7) -> swizzle == sw
        float p[4][4];
        float tmax = -INFINITY;
        #pragma unroll
        for (int kt = 0; kt < 4; ++kt) {
            union { float4 v; float a[4]; } mu;
            mu.v = *(const float4*)(mrl + ((64 * kt + 16 * g) ^ sw));
            #pragma unroll
            for (int r = 0; r < 4; ++r) {
                float sc = st[kt][r] + mu.a[r];
                p[kt][r] = sc;
                tmax = fmaxf(tmax, sc);
            }
        }
        tmax = fmaxf(tmax, __shfl_xor(tmax, 16, 64));
        tmax = fmaxf(tmax, __shfl_xor(tmax, 32, 64));
        float m_new = fmaxf(m_run, tmax);
        float scale = __expf(m_run - m_new);
        float tsum = 0.f;
        #pragma unroll
        for (int kt = 0; kt < 4; ++kt)
            #pragma unroll
            for (int r = 0; r < 4; ++r) {
                float e = __expf(p[kt][r] - m_new);
                p[kt][r] = e;
                tsum += e;
            }
        tsum += __shfl_xor(tsum, 16, 64);
        tsum += __shfl_xor(tsum, 32, 64);
        l_run = l_run * scale + tsum;
        m_run = m_new;
        #pragma unroll
        for (int mt = 0; mt < 4; ++mt) o[mt] *= scale;

        // ---------- P -> bf16 B-fragments via ds_bpermute ----------
        uint32_t w[4][2];
        #pragma unroll
        for (int kt = 0; kt < 4; ++kt) {
            w[kt][0] = ((uint32_t)f2bf(p[kt][1]) << 16) | f2bf(p[kt][0]);
            w[kt][1] = ((uint32_t)f2bf(p[kt][3]) << 16) | f2bf(p[kt][2]);
        }
        bf16x8 pf[2];
        const bool hi_half = (lane & 32) != 0;
        #pragma unroll
        for (int f = 0; f < 2; ++f) {
            uint32_t words[4];
            #pragma unroll
            for (int pp = 0; pp < 4; ++pp) {
                int srcl = 16 * (2 * (g & 1) + (pp >> 1)) + c;
                int addr = srcl << 2;
                int lo = __builtin_amdgcn_ds_bpermute(addr, (int)w[2 * f][pp & 1]);
                int hi = __builtin_amdgcn_ds_bpermute(addr, (int)w[2 * f + 1][pp & 1]);
                words[pp] = hi_half ? (uint32_t)hi : (uint32_t)lo;
            }
            union { uint32_t u[4]; bf16x8 v; } cv;
            cv.u[0] = words[0]; cv.u[1] = words[1];
            cv.u[2] = words[2]; cv.u[3] = words[3];
            pf[f] = cv.v;
        }

        // ---------- PV ----------
        #pragma unroll
        for (int f = 0; f < 2; ++f) {
            #pragma unroll
            for (int mt = 0; mt < 4; ++mt) {
                const unsigned char* base = vlds + (16 * mt + c) * 128;
                bf16x8 vf = *(const bf16x8*)(base + ((64 * f + 16 * g) ^ sw));
                o[mt] = __builtin_amdgcn_mfma_f32_16x16x32_bf16(vf, pf[f], o[mt], 0, 0, 0);
            }
        }
        __syncthreads();
    }

    float inv = 1.0f / l_run;
    float* op = O + qkv_base + (long)qrow * D_DIM;
    #pragma unroll
    for (int mt = 0; mt < 4; ++mt) {
        float4 x = make_float4(o[mt][0] * inv, o[mt][1] * inv,
                               o[mt][2] * inv, o[mt][3] * inv);
        *(float4*)(op + 16 * mt + 4 * g) = x;
    }
}

// ---------- fallback: the round-6 passing kernel (used iff ws too small) ----------
__global__ __launch_bounds__(256, 3)
void attn_fwd(const float* __restrict__ Q, const float* __restrict__ K,
              const float* __restrict__ V, const float* __restrict__ M,
              float* __restrict__ O)
{
    __shared__ unsigned char klds_h[64 * 128];
    __shared__ unsigned char klds_l[64 * 128];
    __shared__ unsigned char vlds[64 * 128];

    const int bid  = blockIdx.x;
    const int bh   = bid >> 5;
    const int qb   = bid & 31;
    const int b    = bh / HEADS;
    const long qkv_base  = (long)bh * S_LEN * D_DIM;
    const long mask_base = (long)b * S_LEN * S_LEN;

    const int tid  = threadIdx.x;
    const int wave = tid >> 6;
    const int lane = tid & 63;
    const int c    = lane & 15;
    const int g    = lane >> 4;
    const int sw   = (c & 7) << 4;

    const int qrow = qb * QBLK + wave * 16 + c;

    bf16x8 qfh[2], qfl[2];
    {
        const float* qp = Q + qkv_base + (long)qrow * D_DIM;
        #pragma unroll
        for (int f = 0; f < 2; ++f) {
            float4 x0 = *(const float4*)(qp + f * 32 + 8 * g);
            float4 x1 = *(const float4*)(qp + f * 32 + 8 * g + 4);
            float e[8] = { x0.x, x0.y, x0.z, x0.w, x1.x, x1.y, x1.z, x1.w };
            bf16x8 th, tl;
            #pragma unroll
            for (int j = 0; j < 8; ++j) {
                unsigned short h, l;
                split2(e[j], h, l);
                th[j] = (short)h; tl[j] = (short)l;
            }
            qfh[f] = th; qfl[f] = tl;
        }
    }

    f32x4 o[4] = {};
    float m_run = -INFINITY, l_run = 0.f;
    const float* mrow = M + mask_base + (long)qrow * S_LEN;

    for (int t0 = 0; t0 < NTILES; ++t0) {
        const int k0 = t0 * KVB;
        {
            const float* kp = K + qkv_base + (long)k0 * D_DIM;
            #pragma unroll
            for (int it = 0; it < 4; ++it) {
                int i   = tid + 256 * it;
                int row = i >> 4;
                int c4  = i & 15;
                float4 x = *(const float4*)(kp + row * 64 + c4 * 4);
                unsigned short h0, l0, h1, l1, h2, l2, h3, l3;
                split2(x.x, h0, l0); split2(x.y, h1, l1);
                split2(x.z, h2, l2); split2(x.w, h3, l3);
                int off = row * 128 + ((c4 * 8) ^ ((row & 7) << 4));
                *(uint2*)(klds_h + off) =
                    make_uint2(((uint32_t)h1 << 16) | h0, ((uint32_t)h3 << 16) | h2);
                *(uint2*)(klds_l + off) =
                    make_uint2(((uint32_t)l1 << 16) | l0, ((uint32_t)l3 << 16) | l2);
            }
        }
        {
            const float* vp = V + qkv_base + (long)k0 * D_DIM;
            int d = tid & 63, a = tid >> 6;
            #pragma unroll
            for (int h = 0; h < 2; ++h) {
                int kk0 = 32 * h + 8 * a;
                float e0 = vp[(kk0 + 0) * 64 + d], e1 = vp[(kk0 + 1) * 64 + d];
                float e2 = vp[(kk0 + 2) * 64 + d], e3 = vp[(kk0 + 3) * 64 + d];
                float e4 = vp[(kk0 + 4) * 64 + d], e5 = vp[(kk0 + 5) * 64 + d];
                float e6 = vp[(kk0 + 6) * 64 + d], e7 = vp[(kk0 + 7) * 64 + d];
                uint32_t w0 = ((uint32_t)f2bf(e1) << 16) | f2bf(e0);
                uint32_t w1 = ((uint32_t)f2bf(e3) << 16) | f2bf(e2);
                uint32_t w2 = ((uint32_t)f2bf(e5) << 16) | f2bf(e4);
                uint32_t w3 = ((uint32_t)f2bf(e7) << 16) | f2bf(e6);
                int off = d * 128 + ((kk0 * 2) ^ ((d & 7) << 4));
                *(uint4*)(vlds + off) = make_uint4(w0, w1, w2, w3);
            }
        }
        __syncthreads();

        f32x4 st[4];
        #pragma unroll
        for (int kt = 0; kt < 4; ++kt) {
            const unsigned char* bh_ = klds_h + (16 * kt + c) * 128;
            const unsigned char* bl_ = klds_l + (16 * kt + c) * 128;
            bf16x8 kh0 = *(const bf16x8*)(bh_ + ((16 * g) ^ sw));
            bf16x8 kh1 = *(const bf16x8*)(bh_ + ((64 + 16 * g) ^ sw));
            bf16x8 kl0 = *(const bf16x8*)(bl_ + ((16 * g) ^ sw));
            bf16x8 kl1 = *(const bf16x8*)(bl_ + ((64 + 16 * g) ^ sw));
            f32x4 acc = {};
            acc = __builtin_amdgcn_mfma_f32_16x16x32_bf16(kh0, qfl[0], acc, 0, 0, 0);
            acc = __builtin_amdgcn_mfma_f32_16x16x32_bf16(kh1, qfl[1], acc, 0, 0, 0);
            acc = __builtin_amdgcn_mfma_f32_16x16x32_bf16(kl0, qfh[0], acc, 0, 0, 0);
            acc = __builtin_amdgcn_mfma_f32_16x16x32_bf16(kl1, qfh[1], acc, 0, 0, 0);
            acc = __builtin_amdgcn_mfma_f32_16x16x32_bf16(kh0, qfh[0], acc, 0, 0, 0);
            acc = __builtin_amdgcn_mfma_f32_16x16x32_bf16(kh1, qfh[1], acc, 0, 0, 0);
            st[kt] = acc;
        }

        float p[4][4];
        float tmax = -INFINITY;
        #pragma unroll
        for (int kt = 0; kt < 4; ++kt)
            #pragma unroll
            for (int r = 0; r < 4; ++r) {
                float sc = st[kt][r] + mrow[k0 + 16 * kt + 4 * g + r];
                p[kt][r] = sc;
                tmax = fmaxf(tmax, sc);
            }
        tmax = fmaxf(tmax, __shfl_xor(tmax, 16, 64));
        tmax = fmaxf(tmax, __shfl_xor(tmax, 32, 64));
        float m_new = fmaxf(m_run, tmax);
        float scale = __expf(m_run - m_new);
        float tsum = 0.f;
        #pragma unroll
        for (int kt = 0; kt < 4; ++kt)
            #pragma unroll
            for (int r = 0; r < 4; ++r) {
                float e = __expf(p[kt][r] - m_new);
                p[kt][r] = e;
                tsum += e;
            }
        tsum += __shfl_xor(tsum, 16, 64);
        tsum += __shfl_xor(tsum, 32, 64);
        l_run = l_run * scale + tsum;
        m_run = m_new;
        #pragma unroll
        for (int mt = 0; mt < 4; ++mt) o[mt] *= scale;

        uint32_t w[4][2];
        #pragma unroll
        for (int kt = 0; kt < 4; ++kt) {
            w[kt][0] = ((uint32_t)f2bf(p[kt][1]) << 16) | f2bf(p[kt][0]);
            w[kt][1] = ((uint32_t)f2bf(p[kt][3]) << 16) | f2bf(p[kt][2]);
        }
        bf16x8 pf[2];
        const bool hi_half = (lane & 32) != 0;
        #pragma unroll
        for (int f = 0; f < 2; ++f) {
            uint32_t words[4];
            #pragma unroll
            for (int pp = 0; pp < 4; ++pp) {
                int srcl = 16 * (2 * (g & 1) + (pp >> 1)) + c;
                int addr = srcl << 2;
                int lo = __builtin_amdgcn_ds_bpermute(addr, (int)w[2 * f][pp & 1]);
                int hi = __builtin_amdgcn_ds_bpermute(addr, (int)w[2 * f + 1][pp & 1]);
                words[pp] = hi_half ? (uint32_t)hi : (uint32_t)lo;
            }
            union { uint32_t u[4]; bf16x8 v; } cv;
            cv.u[0] = words[0]; cv.u[1] = words[1];
            cv.u[2] = words[2]; cv.u[3] = words[3];
            pf[f] = cv.v;
        }

        #pragma unroll
        for (int f = 0; f < 2; ++f) {
            #pragma unroll
            for (int mt = 0; mt < 4; ++mt) {
                const unsigned char* base = vlds + (16 * mt + c) * 128;
                bf16x8 vf = *(const bf16x8*)(base + ((64 * f + 16 * g) ^ sw));
                o[mt] = __builtin_amdgcn_mfma_f32_16x16x32_bf16(vf, pf[f], o[mt], 0, 0, 0);
            }
        }
        __syncthreads();
    }

    float inv = 1.0f / l_run;
    float* op = O + qkv_base + (long)qrow * D_DIM;
    #pragma unroll
    for (int mt = 0; mt < 4; ++mt) {
        float4 x = make_float4(o[mt][0] * inv, o[mt][1] * inv,
                               o[mt][2] * inv, o[mt][3] * inv);
        *(float4*)(op + 16 * mt + 4 * g) = x;
    }
}

extern "C" void kernel_launch(void* const* d_in, const int* in_sizes, int n_in,
                              void* d_out, int out_size, void* d_ws, size_t ws_size,
                              hipStream_t stream) {
    const float* q = (const float*)d_in[0];
    const float* k = (const float*)d_in[1];
    const float* v = (const float*)d_in[2];
    const float* m = (const float*)d_in[3];
    float* o = (float*)d_out;
    dim3 grid(BH * (S_LEN / QBLK));      // 768
    dim3 block(256);
    if (ws_size >= WS_NEED) {
        convert_kv<<<grid, block, 0, stream>>>(k, v, (unsigned char*)d_ws);
        attn_fwd_ws<<<grid, block, 0, stream>>>(q, m, (const unsigned char*)d_ws, o);
    } else {
        attn_fwd<<<grid, block, 0, stream>>>(q, k, v, m, o);
    }
}